// Round 1
// baseline (564.787 us; speedup 1.0000x reference)
//
#include <hip/hip_runtime.h>
#include <hip/hip_bf16.h>

// Net_79018808312147: x[D]; W_in[D,D]; b_in[D]; weights[L,D,D]; orders[L,D,D];
// biases[L,D]; gather_idx[L,D] (int32); scatter_idx[L+1,D] (int32 permutations).
// out = last layer's pre-scatter relu((W*O)@inp + b), [D] float32.
//
// Memory-bound: must stream 604 MB (W_in + weights + orders) per call.
// Structure: 5 dependent GEMV launches; gather staged to LDS per block;
// scatter fused into epilogue (permutation => full overwrite, no zeroing).

#define DD 4096
#define BLOCK 1024   // 16 waves per block
#define GRID 256     // 16 rows per block (1 row per wave), 256 blocks = 1/CU

template<bool MASKED>
__global__ __launch_bounds__(BLOCK, 4)
void gemv_kernel(const float* __restrict__ W,
                 const float* __restrict__ O,
                 const float* __restrict__ bias,
                 const float* __restrict__ src,   // prev node buffer (or x for layer 0)
                 const int*   __restrict__ g,     // gather idx (null for layer 0)
                 const int*   __restrict__ s,     // scatter idx (null for final layer)
                 float*       __restrict__ dst)   // next node buffer, or d_out
{
    __shared__ float sh[DD];
    const int tid = threadIdx.x;

    // Stage (gathered) input vector into LDS: 4096 floats = 16 KiB.
    #pragma unroll
    for (int j = tid; j < DD; j += BLOCK) {
        sh[j] = MASKED ? src[g[j]] : src[j];
    }
    __syncthreads();

    const int lane = tid & 63;
    const int wv   = tid >> 6;                 // 0..15
    const int row  = blockIdx.x * 16 + wv;     // one output row per wave

    const float* __restrict__ Wr = W + (size_t)row * DD;
    const float* __restrict__ Or = MASKED ? (O + (size_t)row * DD) : nullptr;

    float acc = 0.f;
    #pragma unroll 4
    for (int it = 0; it < 16; ++it) {
        const int col = it * 256 + lane * 4;   // 64 lanes * float4 = 256 cols/iter
        float4 w = *reinterpret_cast<const float4*>(Wr + col);
        float4 v = *reinterpret_cast<const float4*>(sh + col);
        if (MASKED) {
            float4 o = *reinterpret_cast<const float4*>(Or + col);
            w.x *= o.x; w.y *= o.y; w.z *= o.z; w.w *= o.w;
        }
        acc = fmaf(w.x, v.x, acc);
        acc = fmaf(w.y, v.y, acc);
        acc = fmaf(w.z, v.z, acc);
        acc = fmaf(w.w, v.w, acc);
    }

    // Wave-level reduction (64 lanes).
    #pragma unroll
    for (int off = 32; off > 0; off >>= 1)
        acc += __shfl_xor(acc, off, 64);

    if (lane == 0) {
        float r = fmaxf(acc + bias[row], 0.f);
        if (s) dst[s[row]] = r;   // scatter into next node buffer (permutation)
        else   dst[row]    = r;   // final layer: pre-scatter output
    }
}

extern "C" void kernel_launch(void* const* d_in, const int* in_sizes, int n_in,
                              void* d_out, int out_size, void* d_ws, size_t ws_size,
                              hipStream_t stream) {
    const float* x       = (const float*)d_in[0];
    const float* W_in    = (const float*)d_in[1];
    const float* b_in    = (const float*)d_in[2];
    const float* weights = (const float*)d_in[3];
    const float* orders  = (const float*)d_in[4];
    const float* biases  = (const float*)d_in[5];
    const int*   gidx    = (const int*)d_in[6];
    const int*   sidx    = (const int*)d_in[7];
    float*       out     = (float*)d_out;

    float* buf0 = (float*)d_ws;
    float* buf1 = buf0 + DD;

    // Input layer: relu(W_in @ x + b_in), scattered by scatter_idx[0].
    gemv_kernel<false><<<GRID, BLOCK, 0, stream>>>(
        W_in, nullptr, b_in, x, nullptr, sidx, buf0);

    float* cur = buf0;
    float* nxt = buf1;
    for (int l = 0; l < 4; ++l) {
        const int* s  = (l == 3) ? nullptr : (sidx + (size_t)(l + 1) * DD);
        float*     d  = (l == 3) ? out     : nxt;
        gemv_kernel<true><<<GRID, BLOCK, 0, stream>>>(
            weights + (size_t)l * DD * DD,
            orders  + (size_t)l * DD * DD,
            biases  + (size_t)l * DD,
            cur, gidx + (size_t)l * DD, s, d);
        float* t = cur; cur = nxt; nxt = t;
    }
}

// Round 2
// 558.581 us; speedup vs baseline: 1.0111x; 1.0111x over previous
//
#include <hip/hip_runtime.h>
#include <hip/hip_bf16.h>

// Net_79018808312147: x[D]; W_in[D,D]; b_in[D]; weights[L,D,D]; orders[L,D,D];
// biases[L,D]; gather_idx[L,D] (int32); scatter_idx[L+1,D] (int32 permutations).
// out = last layer's pre-scatter relu((W*O)@inp + b), [D] float32.
//
// Memory-bound: 604 MB mandatory stream (W_in + weights + orders) per call.
// R1 hit only 1.07 TB/s: ~8 outstanding loads/wave (unroll 4) -> latency-bound.
// R2: batch the full 16 KB row (16 W + 16 O float4 loads) into registers
// up-front for ~512 B/wave in flight (~8 KB/CU at 16 waves/CU), then drain
// through 4 independent FMA chains.

#define DD 4096
#define BLOCK 512    // 8 waves per block, one output row per wave
#define GRID  512    // 8 rows/block * 512 blocks = 4096 rows; 2 blocks/CU

template<bool MASKED>
__global__ __launch_bounds__(BLOCK)
void gemv_kernel(const float* __restrict__ W,
                 const float* __restrict__ O,
                 const float* __restrict__ bias,
                 const float* __restrict__ src,   // prev node buffer (or x)
                 const int*   __restrict__ g,     // gather idx (null layer 0)
                 const int*   __restrict__ s,     // scatter idx (null final)
                 float*       __restrict__ dst)
{
    __shared__ float sh[DD];
    const int tid = threadIdx.x;

    // Stage (gathered) input vector into LDS: 4096 floats = 16 KiB.
    #pragma unroll
    for (int j = tid; j < DD; j += BLOCK)
        sh[j] = MASKED ? src[g[j]] : src[j];
    __syncthreads();

    const int lane = tid & 63;
    const int wv   = tid >> 6;                // 0..7
    const int row  = blockIdx.x * 8 + wv;

    const float* __restrict__ Wr = W + (size_t)row * DD + lane * 4;
    const float* __restrict__ Or = MASKED ? (O + (size_t)row * DD + lane * 4)
                                          : nullptr;

    // Batch the whole row into registers: 32 independent 16B loads in flight.
    float4 w[16];
    #pragma unroll
    for (int it = 0; it < 16; ++it)
        w[it] = *reinterpret_cast<const float4*>(Wr + it * 256);

    float4 o[16];
    if (MASKED) {
        #pragma unroll
        for (int it = 0; it < 16; ++it)
            o[it] = *reinterpret_cast<const float4*>(Or + it * 256);
    }

    // Drain: 4 independent accumulator chains.
    float a0 = 0.f, a1 = 0.f, a2 = 0.f, a3 = 0.f;
    #pragma unroll
    for (int it = 0; it < 16; ++it) {
        float4 v = *reinterpret_cast<const float4*>(sh + it * 256 + lane * 4);
        float4 ww = w[it];
        if (MASKED) {
            ww.x *= o[it].x; ww.y *= o[it].y; ww.z *= o[it].z; ww.w *= o[it].w;
        }
        a0 = fmaf(ww.x, v.x, a0);
        a1 = fmaf(ww.y, v.y, a1);
        a2 = fmaf(ww.z, v.z, a2);
        a3 = fmaf(ww.w, v.w, a3);
    }
    float acc = (a0 + a1) + (a2 + a3);

    // Wave-level reduction (64 lanes).
    #pragma unroll
    for (int off = 32; off > 0; off >>= 1)
        acc += __shfl_xor(acc, off, 64);

    if (lane == 0) {
        float r = fmaxf(acc + bias[row], 0.f);
        if (s) dst[s[row]] = r;   // scatter into next node buffer (permutation)
        else   dst[row]    = r;   // final layer: pre-scatter output
    }
}

extern "C" void kernel_launch(void* const* d_in, const int* in_sizes, int n_in,
                              void* d_out, int out_size, void* d_ws, size_t ws_size,
                              hipStream_t stream) {
    const float* x       = (const float*)d_in[0];
    const float* W_in    = (const float*)d_in[1];
    const float* b_in    = (const float*)d_in[2];
    const float* weights = (const float*)d_in[3];
    const float* orders  = (const float*)d_in[4];
    const float* biases  = (const float*)d_in[5];
    const int*   gidx    = (const int*)d_in[6];
    const int*   sidx    = (const int*)d_in[7];
    float*       out     = (float*)d_out;

    float* buf0 = (float*)d_ws;
    float* buf1 = buf0 + DD;

    // Input layer: relu(W_in @ x + b_in), scattered by scatter_idx[0].
    gemv_kernel<false><<<GRID, BLOCK, 0, stream>>>(
        W_in, nullptr, b_in, x, nullptr, sidx, buf0);

    float* cur = buf0;
    float* nxt = buf1;
    for (int l = 0; l < 4; ++l) {
        const int* s  = (l == 3) ? nullptr : (sidx + (size_t)(l + 1) * DD);
        float*     d  = (l == 3) ? out     : nxt;
        gemv_kernel<true><<<GRID, BLOCK, 0, stream>>>(
            weights + (size_t)l * DD * DD,
            orders  + (size_t)l * DD * DD,
            biases  + (size_t)l * DD,
            cur, gidx + (size_t)l * DD, s, d);
        float* t = cur; cur = nxt; nxt = t;
    }
}